// Round 1
// baseline (1509.363 us; speedup 1.0000x reference)
//
#include <hip/hip_runtime.h>
#include <hip/hip_bf16.h>
#include <cmath>

#define LNEPS 1e-5f

__device__ __forceinline__ float bflo(unsigned u){ return __uint_as_float(u << 16); }
__device__ __forceinline__ float bfhi(unsigned u){ return __uint_as_float(u & 0xffff0000u); }
__device__ __forceinline__ unsigned short f2bf(float f){
  unsigned u = __float_as_uint(f);
  u += 0x7fffu + ((u >> 16) & 1u);
  return (unsigned short)(u >> 16);
}
__device__ __forceinline__ void bf16x16_to_f32(const unsigned short* p, float* d){
  const uint4 u0 = *(const uint4*)p;
  const uint4 u1 = *(const uint4*)(p + 8);
  d[0]=bflo(u0.x); d[1]=bfhi(u0.x); d[2]=bflo(u0.y); d[3]=bfhi(u0.y);
  d[4]=bflo(u0.z); d[5]=bfhi(u0.z); d[6]=bflo(u0.w); d[7]=bfhi(u0.w);
  d[8]=bflo(u1.x); d[9]=bfhi(u1.x); d[10]=bflo(u1.y); d[11]=bfhi(u1.y);
  d[12]=bflo(u1.z); d[13]=bfhi(u1.z); d[14]=bflo(u1.w); d[15]=bfhi(u1.w);
}

// ---------------- K1: LN1 + shift + window partition -> win[131072][128] ----------------
__global__ __launch_bounds__(256) void k1_ln1_window(
    const float* __restrict__ x, const float* __restrict__ gw, const float* __restrict__ gb,
    float* __restrict__ win)
{
  const int lane = threadIdx.x & 63;
  const int wave = threadIdx.x >> 6;
  const int row  = blockIdx.x * 4 + wave;            // window-ordered row
  const int wid = row >> 6, n = row & 63;
  const int b = wid >> 10, rem = wid & 1023;
  const int wh = rem >> 5, wwi = rem & 31;
  const int i = n >> 3, j = n & 7;
  const int sh = (wh * 8 + i + 4) & 255;             // roll(-SHIFT): src = (pos+4)%256
  const int sw = (wwi * 8 + j + 4) & 255;
  const float2 v = *(const float2*)(x + (((size_t)b << 16) + sh * 256 + sw) * 128 + lane * 2);
  float s = v.x + v.y, ss = v.x * v.x + v.y * v.y;
  #pragma unroll
  for (int o = 1; o < 64; o <<= 1) { s += __shfl_xor(s, o); ss += __shfl_xor(ss, o); }
  const float mean = s * 0.0078125f;
  const float rstd = rsqrtf(ss * 0.0078125f - mean * mean + LNEPS);
  const float2 w2 = *(const float2*)(gw + lane * 2);
  const float2 b2 = *(const float2*)(gb + lane * 2);
  float2 o2;
  o2.x = (v.x - mean) * rstd * w2.x + b2.x;
  o2.y = (v.y - mean) * rstd * w2.y + b2.y;
  *(float2*)(win + (size_t)row * 128 + lane * 2) = o2;
}

// ---------------- K2: qkv GEMM (M=131072,K=128,N=384) -> bf16 qkv ----------------
__global__ __launch_bounds__(256) void k2_qkv(
    const float* __restrict__ A, const float* __restrict__ W,
    const float* __restrict__ bias, unsigned short* __restrict__ qkv)
{
  __shared__ float At[128 * 64];   // [k][m]
  __shared__ float Bt[128 * 64];   // [k][n]
  const int t = threadIdx.x;
  const int wid = blockIdx.x, nt = blockIdx.y;
  const float4* Ag = (const float4*)(A + (size_t)wid * 8192);
  const float4* Wg = (const float4*)(W + (size_t)nt * 8192);
  #pragma unroll
  for (int it = 0; it < 8; ++it) {
    const int f = it * 256 + t;
    const int r = f >> 5, k0 = (f & 31) * 4;
    const float4 a = Ag[f], w = Wg[f];
    At[(k0 + 0) * 64 + r] = a.x; At[(k0 + 1) * 64 + r] = a.y;
    At[(k0 + 2) * 64 + r] = a.z; At[(k0 + 3) * 64 + r] = a.w;
    Bt[(k0 + 0) * 64 + r] = w.x; Bt[(k0 + 1) * 64 + r] = w.y;
    Bt[(k0 + 2) * 64 + r] = w.z; Bt[(k0 + 3) * 64 + r] = w.w;
  }
  __syncthreads();
  const int tx = t & 15, ty = t >> 4;
  const int r0 = ty * 4, c0 = tx * 4;
  float acc[4][4] = {};
  #pragma unroll 8
  for (int k = 0; k < 128; ++k) {
    const float4 a = *(const float4*)&At[k * 64 + r0];
    const float4 w = *(const float4*)&Bt[k * 64 + c0];
    const float ax[4] = {a.x, a.y, a.z, a.w};
    const float wx[4] = {w.x, w.y, w.z, w.w};
    #pragma unroll
    for (int i2 = 0; i2 < 4; ++i2)
      #pragma unroll
      for (int j2 = 0; j2 < 4; ++j2)
        acc[i2][j2] = fmaf(ax[i2], wx[j2], acc[i2][j2]);
  }
  const float4 bv = *(const float4*)&bias[nt * 64 + c0];
  #pragma unroll
  for (int i2 = 0; i2 < 4; ++i2) {
    ushort4 o;
    o.x = f2bf(acc[i2][0] + bv.x);
    o.y = f2bf(acc[i2][1] + bv.y);
    o.z = f2bf(acc[i2][2] + bv.z);
    o.w = f2bf(acc[i2][3] + bv.w);
    *(ushort4*)&qkv[((size_t)wid * 64 + r0 + i2) * 384 + nt * 64 + c0] = o;
  }
}

// ---------------- K3: window attention, one wave per (window, head) ----------------
__global__ __launch_bounds__(256) void k3_attn(
    const unsigned short* __restrict__ qkv,
    const float* __restrict__ table,   // (225, 8)
    float* __restrict__ out)           // [131072][128], head-concatenated
{
  __shared__ float Ks[4][64 * 16];
  __shared__ float Vs[4][64 * 16];
  __shared__ float Tb[1800];
  const int t = threadIdx.x;
  for (int idx = t; idx < 1800; idx += 256) Tb[idx] = table[idx];
  const int wave = t >> 6, lane = t & 63;
  const int id = blockIdx.x * 4 + wave;
  const int wid = id >> 3, h = id & 7;
  const unsigned short* base = qkv + (size_t)wid * 64 * 384 + lane * 384 + h * 16;
  float q[16];
  bf16x16_to_f32(base, q);
  #pragma unroll
  for (int d = 0; d < 16; ++d) q[d] *= 0.25f;       // scale = HD^-0.5
  bf16x16_to_f32(base + 128, &Ks[wave][lane * 16]);
  bf16x16_to_f32(base + 256, &Vs[wave][lane * 16]);
  __syncthreads();
  const int i1 = lane >> 3, j1 = lane & 7;
  const float* kk = &Ks[wave][0];
  float s[64];
  float mx = -1e30f;
  #pragma unroll
  for (int m = 0; m < 64; ++m) {
    float acc = 0.f;
    #pragma unroll
    for (int d = 0; d < 16; ++d) acc = fmaf(q[d], kk[m * 16 + d], acc);
    const int i2 = m >> 3, j2 = m & 7;
    acc += Tb[((i1 - i2 + 7) * 15 + (j1 - j2 + 7)) * 8 + h];
    s[m] = acc;
    mx = fmaxf(mx, acc);
  }
  float sum = 0.f;
  #pragma unroll
  for (int m = 0; m < 64; ++m) { const float e = __expf(s[m] - mx); s[m] = e; sum += e; }
  float o[16] = {};
  const float* vv = &Vs[wave][0];
  #pragma unroll
  for (int m = 0; m < 64; ++m) {
    const float p = s[m];
    #pragma unroll
    for (int d = 0; d < 16; ++d) o[d] = fmaf(p, vv[m * 16 + d], o[d]);
  }
  const float inv = 1.f / sum;
  float* dst = out + ((size_t)wid * 64 + lane) * 128 + h * 16;
  #pragma unroll
  for (int d4 = 0; d4 < 4; ++d4) {
    float4 ov = { o[d4*4+0]*inv, o[d4*4+1]*inv, o[d4*4+2]*inv, o[d4*4+3]*inv };
    *(float4*)(dst + d4 * 4) = ov;
  }
}

// ---------------- K4: proj GEMM + window reverse + unshift + residual -> x2 (=d_out) ----------------
__global__ __launch_bounds__(256) void k4_proj(
    const float* __restrict__ A,      // attn_out [131072][128]
    const float* __restrict__ W,      // proj_w (128,128)
    const float* __restrict__ bias,
    const float* __restrict__ xin,    // shortcut x
    float* __restrict__ out)          // x2 = d_out
{
  __shared__ float At[128 * 64];
  __shared__ float Bt[128 * 64];
  const int t = threadIdx.x;
  const int wid = blockIdx.x, nt = blockIdx.y;     // nt in 0..1
  const float4* Ag = (const float4*)(A + (size_t)wid * 8192);
  const float4* Wg = (const float4*)(W + (size_t)nt * 8192);
  #pragma unroll
  for (int it = 0; it < 8; ++it) {
    const int f = it * 256 + t;
    const int r = f >> 5, k0 = (f & 31) * 4;
    const float4 a = Ag[f], w = Wg[f];
    At[(k0 + 0) * 64 + r] = a.x; At[(k0 + 1) * 64 + r] = a.y;
    At[(k0 + 2) * 64 + r] = a.z; At[(k0 + 3) * 64 + r] = a.w;
    Bt[(k0 + 0) * 64 + r] = w.x; Bt[(k0 + 1) * 64 + r] = w.y;
    Bt[(k0 + 2) * 64 + r] = w.z; Bt[(k0 + 3) * 64 + r] = w.w;
  }
  __syncthreads();
  const int tx = t & 15, ty = t >> 4;
  const int r0 = ty * 4, c0 = tx * 4;
  float acc[4][4] = {};
  #pragma unroll 8
  for (int k = 0; k < 128; ++k) {
    const float4 a = *(const float4*)&At[k * 64 + r0];
    const float4 w = *(const float4*)&Bt[k * 64 + c0];
    const float ax[4] = {a.x, a.y, a.z, a.w};
    const float wx[4] = {w.x, w.y, w.z, w.w};
    #pragma unroll
    for (int i2 = 0; i2 < 4; ++i2)
      #pragma unroll
      for (int j2 = 0; j2 < 4; ++j2)
        acc[i2][j2] = fmaf(ax[i2], wx[j2], acc[i2][j2]);
  }
  const int b = wid >> 10, rem = wid & 1023;
  const int wh = rem >> 5, wwi = rem & 31;
  const float4 bv = *(const float4*)&bias[nt * 64 + c0];
  #pragma unroll
  for (int i2 = 0; i2 < 4; ++i2) {
    const int n = r0 + i2;
    const int si = n >> 3, sj = n & 7;
    const int hd_ = (wh * 8 + si + 4) & 255;      // roll(+SHIFT)
    const int wd_ = (wwi * 8 + sj + 4) & 255;
    const size_t off = (((size_t)b << 16) + hd_ * 256 + wd_) * 128 + nt * 64 + c0;
    const float4 xv = *(const float4*)(xin + off);
    float4 o;
    o.x = xv.x + acc[i2][0] + bv.x;
    o.y = xv.y + acc[i2][1] + bv.y;
    o.z = xv.z + acc[i2][2] + bv.z;
    o.w = xv.w + acc[i2][3] + bv.w;
    *(float4*)(out + off) = o;
  }
}

// ---------------- K5: fused LN2 + fc1 + GELU + fc2 + residual ----------------
__global__ __launch_bounds__(256) void k5_mlp(
    const float* __restrict__ x2,
    const float* __restrict__ gw, const float* __restrict__ gb,
    const float* __restrict__ w1, const float* __restrict__ b1,
    const float* __restrict__ w2, const float* __restrict__ b2,
    float* __restrict__ out)
{
  __shared__ float At[128 * 64];    // ln2(x2), [k][row]
  __shared__ float Buf[128 * 64];   // W1 tile then W2 tile (time-shared)
  __shared__ float Ht[64 * 64];     // h subtile [kk][row]; aliased as LN partials at start
  const int t = threadIdx.x;
  const size_t row0 = (size_t)blockIdx.x * 64;
  {
    const int rr = t >> 2, qq = t & 3;
    const float* src = x2 + (row0 + rr) * 128 + qq * 32;
    float v[32];
    float s = 0.f, ss = 0.f;
    #pragma unroll
    for (int k4 = 0; k4 < 8; ++k4) {
      const float4 a = *(const float4*)(src + k4 * 4);
      v[k4*4+0]=a.x; v[k4*4+1]=a.y; v[k4*4+2]=a.z; v[k4*4+3]=a.w;
      s  += a.x + a.y + a.z + a.w;
      ss += a.x*a.x + a.y*a.y + a.z*a.z + a.w*a.w;
    }
    float* red = Ht;
    red[(rr * 4 + qq) * 2 + 0] = s;
    red[(rr * 4 + qq) * 2 + 1] = ss;
    __syncthreads();
    s  = red[rr*8+0] + red[rr*8+2] + red[rr*8+4] + red[rr*8+6];
    ss = red[rr*8+1] + red[rr*8+3] + red[rr*8+5] + red[rr*8+7];
    const float mean = s * 0.0078125f;
    const float rstd = rsqrtf(ss * 0.0078125f - mean * mean + LNEPS);
    #pragma unroll
    for (int k = 0; k < 32; ++k) {
      const int cc = qq * 32 + k;
      At[cc * 64 + rr] = (v[k] - mean) * rstd * gw[cc] + gb[cc];
    }
  }
  const int tx = t & 15, ty = t >> 4;
  const int r0 = ty * 4;
  float oacc[4][8] = {};   // cols: 4tx+j (j<4), 64+4tx+(j-4)
  for (int s8 = 0; s8 < 8; ++s8) {
    __syncthreads();   // At ready (iter 0); prev iter's Buf/Ht reads done
    const float4* Wg = (const float4*)(w1 + (size_t)s8 * 8192);
    #pragma unroll
    for (int it = 0; it < 8; ++it) {
      const int f = it * 256 + t;
      const int r = f >> 5, k0 = (f & 31) * 4;
      const float4 w = Wg[f];
      Buf[(k0 + 0) * 64 + r] = w.x; Buf[(k0 + 1) * 64 + r] = w.y;
      Buf[(k0 + 2) * 64 + r] = w.z; Buf[(k0 + 3) * 64 + r] = w.w;
    }
    __syncthreads();
    float acc1[4][4] = {};
    #pragma unroll 4
    for (int k = 0; k < 128; ++k) {
      const float4 a = *(const float4*)&At[k * 64 + r0];
      const float4 w = *(const float4*)&Buf[k * 64 + tx * 4];
      const float ax[4] = {a.x, a.y, a.z, a.w};
      const float wx[4] = {w.x, w.y, w.z, w.w};
      #pragma unroll
      for (int i2 = 0; i2 < 4; ++i2)
        #pragma unroll
        for (int j2 = 0; j2 < 4; ++j2)
          acc1[i2][j2] = fmaf(ax[i2], wx[j2], acc1[i2][j2]);
    }
    __syncthreads();   // Buf (W1) reads done -> can overwrite with W2
    const float4 b1v = *(const float4*)&b1[s8 * 64 + tx * 4];
    const float b1a[4] = {b1v.x, b1v.y, b1v.z, b1v.w};
    #pragma unroll
    for (int i2 = 0; i2 < 4; ++i2)
      #pragma unroll
      for (int j2 = 0; j2 < 4; ++j2) {
        float hv = acc1[i2][j2] + b1a[j2];
        hv = 0.5f * hv * (1.f + erff(hv * 0.70710678118654752f));   // exact GELU
        Ht[(tx * 4 + j2) * 64 + (r0 + i2)] = hv;
      }
    #pragma unroll
    for (int it = 0; it < 8; ++it) {
      const int f = it * 256 + t;
      const int c = f >> 4, k4 = (f & 15) * 4;
      const float4 w = *(const float4*)(w2 + (size_t)c * 512 + s8 * 64 + k4);
      Buf[(k4 + 0) * 128 + c] = w.x; Buf[(k4 + 1) * 128 + c] = w.y;
      Buf[(k4 + 2) * 128 + c] = w.z; Buf[(k4 + 3) * 128 + c] = w.w;
    }
    __syncthreads();   // Ht + W2 ready
    #pragma unroll 4
    for (int kk2 = 0; kk2 < 64; ++kk2) {
      const float4 a   = *(const float4*)&Ht[kk2 * 64 + r0];
      const float4 blo = *(const float4*)&Buf[kk2 * 128 + tx * 4];
      const float4 bhi = *(const float4*)&Buf[kk2 * 128 + 64 + tx * 4];
      const float ax[4] = {a.x, a.y, a.z, a.w};
      const float bl[4] = {blo.x, blo.y, blo.z, blo.w};
      const float bh[4] = {bhi.x, bhi.y, bhi.z, bhi.w};
      #pragma unroll
      for (int i2 = 0; i2 < 4; ++i2) {
        #pragma unroll
        for (int j2 = 0; j2 < 4; ++j2) {
          oacc[i2][j2]     = fmaf(ax[i2], bl[j2], oacc[i2][j2]);
          oacc[i2][j2 + 4] = fmaf(ax[i2], bh[j2], oacc[i2][j2 + 4]);
        }
      }
    }
  }
  const float4 b2lo = *(const float4*)&b2[tx * 4];
  const float4 b2hi = *(const float4*)&b2[64 + tx * 4];
  #pragma unroll
  for (int i2 = 0; i2 < 4; ++i2) {
    const size_t off = (row0 + r0 + i2) * 128;
    const float4 xlo = *(const float4*)(x2 + off + tx * 4);
    const float4 xhi = *(const float4*)(x2 + off + 64 + tx * 4);
    float4 olo, ohi;
    olo.x = xlo.x + oacc[i2][0] + b2lo.x;
    olo.y = xlo.y + oacc[i2][1] + b2lo.y;
    olo.z = xlo.z + oacc[i2][2] + b2lo.z;
    olo.w = xlo.w + oacc[i2][3] + b2lo.w;
    ohi.x = xhi.x + oacc[i2][4] + b2hi.x;
    ohi.y = xhi.y + oacc[i2][5] + b2hi.y;
    ohi.z = xhi.z + oacc[i2][6] + b2hi.z;
    ohi.w = xhi.w + oacc[i2][7] + b2hi.w;
    *(float4*)(out + off + tx * 4) = olo;
    *(float4*)(out + off + 64 + tx * 4) = ohi;
  }
}

extern "C" void kernel_launch(void* const* d_in, const int* in_sizes, int n_in,
                              void* d_out, int out_size, void* d_ws, size_t ws_size,
                              hipStream_t stream)
{
  const float* x    = (const float*)d_in[0];
  const float* n1w  = (const float*)d_in[1];
  const float* n1b  = (const float*)d_in[2];
  const float* qkvw = (const float*)d_in[3];
  const float* qkvb = (const float*)d_in[4];
  const float* relb = (const float*)d_in[5];
  const float* pw   = (const float*)d_in[6];
  const float* pb   = (const float*)d_in[7];
  const float* n2w  = (const float*)d_in[8];
  const float* n2b  = (const float*)d_in[9];
  const float* w1   = (const float*)d_in[10];
  const float* b1   = (const float*)d_in[11];
  const float* w2   = (const float*)d_in[12];
  const float* b2   = (const float*)d_in[13];
  float* out = (float*)d_out;

  float* win = (float*)d_ws;                                        // 16.78M floats (67 MB), reused as attn_out
  unsigned short* qkvs = (unsigned short*)((float*)d_ws + 16777216); // 50.33M bf16 (100 MB)

  k1_ln1_window<<<32768, 256, 0, stream>>>(x, n1w, n1b, win);
  k2_qkv<<<dim3(2048, 6), 256, 0, stream>>>(win, qkvw, qkvb, qkvs);
  k3_attn<<<4096, 256, 0, stream>>>(qkvs, relb, win);
  k4_proj<<<dim3(2048, 2), 256, 0, stream>>>(win, pw, pb, x, out);
  k5_mlp<<<2048, 256, 0, stream>>>(out, n2w, n2b, w1, b1, w2, b2, out);
}

// Round 5
// 251.615 us; speedup vs baseline: 5.9987x; 5.9987x over previous
//
#include <hip/hip_runtime.h>
#include <hip/hip_bf16.h>
#include <cmath>

#define LNEPS 1e-5f

typedef __attribute__((ext_vector_type(8))) short short8v;
typedef __attribute__((ext_vector_type(4))) float f32x4;

__device__ __forceinline__ unsigned short f2bf(float f){
  unsigned u = __float_as_uint(f);
  u += 0x7fffu + ((u >> 16) & 1u);
  return (unsigned short)(u >> 16);
}
__device__ __forceinline__ float gelu_f(float x){
  return 0.5f * x * (1.f + erff(x * 0.70710678118654752f));
}

// Device-guarded MFMA wrapper: host pass must never see target builtins.
__device__ __forceinline__ f32x4 mfma32(short8v a, short8v b, f32x4 c){
#ifdef __HIP_DEVICE_COMPILE__
  return __builtin_amdgcn_mfma_f32_16x16x32_bf16(a, b, c, 0, 0, 0);
#else
  return c;
#endif
}

// Stage 128 rows x 128 bf16 from global [r][ldg] into XOR-swizzled LDS (row stride 256B).
__device__ __forceinline__ void stage128(const unsigned short* g, int ldg, short* lds){
  const int t = threadIdx.x;
  #pragma unroll
  for (int it = 0; it < 8; ++it) {
    const int flat = it * 256 + t;
    const int r = flat >> 4, c = flat & 15;
    const uint4 v = *(const uint4*)(g + (size_t)r * ldg + c * 8);
    *(uint4*)((char*)lds + r * 256 + ((c ^ (r & 7)) << 4)) = v;
  }
}
// Swizzled 16B fragment read: row-major [row][128 bf16], chunk = 16B unit index.
__device__ __forceinline__ short8v frag_ld(const short* lds, int row, int chunk){
  return *(const short8v*)((const char*)lds + row * 256 + ((chunk ^ (row & 7)) << 4));
}

// ---------------- K0: weights f32 -> bf16 ----------------
__global__ __launch_bounds__(256) void k0_cvt(
    const float* __restrict__ qkvw, const float* __restrict__ pw,
    const float* __restrict__ w1, const float* __restrict__ w2,
    unsigned short* __restrict__ dst)
{
  const int i = (blockIdx.x * 256 + threadIdx.x) * 4;
  const float* src; int off;
  if (i < 49152)       { src = qkvw; off = i; }
  else if (i < 65536)  { src = pw;   off = i - 49152; }
  else if (i < 131072) { src = w1;   off = i - 65536; }
  else                 { src = w2;   off = i - 131072; }
  const float4 v = *(const float4*)(src + off);
  ushort4 o = { f2bf(v.x), f2bf(v.y), f2bf(v.z), f2bf(v.w) };
  *(ushort4*)(dst + i) = o;
}

// ---------------- K1: LN1 + shift + window partition -> win bf16 [131072][128] ----------------
__global__ __launch_bounds__(256) void k1_ln1_window(
    const float* __restrict__ x, const float* __restrict__ gw, const float* __restrict__ gb,
    unsigned short* __restrict__ win)
{
  const int lane = threadIdx.x & 63;
  const int wave = threadIdx.x >> 6;
  const int row  = blockIdx.x * 4 + wave;
  const int wid = row >> 6, n = row & 63;
  const int b = wid >> 10, rem = wid & 1023;
  const int wh = rem >> 5, wwi = rem & 31;
  const int i = n >> 3, j = n & 7;
  const int sh = (wh * 8 + i + 4) & 255;
  const int sw = (wwi * 8 + j + 4) & 255;
  const float2 v = *(const float2*)(x + (((size_t)b << 16) + sh * 256 + sw) * 128 + lane * 2);
  float s = v.x + v.y, ss = v.x * v.x + v.y * v.y;
  #pragma unroll
  for (int o = 1; o < 64; o <<= 1) { s += __shfl_xor(s, o); ss += __shfl_xor(ss, o); }
  const float mean = s * 0.0078125f;
  const float rstd = rsqrtf(ss * 0.0078125f - mean * mean + LNEPS);
  const float2 w2 = *(const float2*)(gw + lane * 2);
  const float2 b2 = *(const float2*)(gb + lane * 2);
  const unsigned lo = f2bf((v.x - mean) * rstd * w2.x + b2.x);
  const unsigned hi = f2bf((v.y - mean) * rstd * w2.y + b2.y);
  *(unsigned*)(win + (size_t)row * 128 + lane * 2) = lo | (hi << 16);
}

// ---------------- K2: qkv MFMA GEMM -> qk bf16 [131072][256] + vt bf16 [16384][16][64] ----------------
__global__ __launch_bounds__(256, 2) void k2_qkv(
    const unsigned short* __restrict__ A,
    const unsigned short* __restrict__ Wb,
    const float* __restrict__ bias,
    unsigned short* __restrict__ qk,
    unsigned short* __restrict__ vt)
{
  __shared__ __align__(16) short At[128 * 128];
  __shared__ __align__(16) short Bt[128 * 128];
  const int t = threadIdx.x;
  const int row0 = blockIdx.x * 128, n0 = blockIdx.y * 128;
  stage128(Wb + (size_t)n0 * 128, 128, At);
  stage128(A + (size_t)row0 * 128, 128, Bt);
  __syncthreads();
  const int l = t & 63, w = t >> 6, w0 = w & 1, w1 = w >> 1;
  const int g = l >> 4, rl = l & 15;
  const f32x4 z = {0.f, 0.f, 0.f, 0.f};
  f32x4 acc[4][4];
  #pragma unroll
  for (int i = 0; i < 4; ++i)
    #pragma unroll
    for (int j = 0; j < 4; ++j) acc[i][j] = z;
  #pragma unroll
  for (int kk = 0; kk < 4; ++kk) {
    short8v a[4], b[4];
    #pragma unroll
    for (int i = 0; i < 4; ++i) a[i] = frag_ld(At, w0 * 64 + i * 16 + rl, kk * 4 + g);
    #pragma unroll
    for (int j = 0; j < 4; ++j) b[j] = frag_ld(Bt, w1 * 64 + j * 16 + rl, kk * 4 + g);
    #pragma unroll
    for (int i = 0; i < 4; ++i)
      #pragma unroll
      for (int j = 0; j < 4; ++j)
        acc[i][j] = mfma32(a[i], b[j], acc[i][j]);
  }
  if (blockIdx.y < 2) {
    #pragma unroll
    for (int i = 0; i < 4; ++i) {
      const int np = w0 * 64 + i * 16 + 4 * g;
      const float4 bv = *(const float4*)(bias + n0 + np);
      #pragma unroll
      for (int j = 0; j < 4; ++j) {
        const int r = row0 + w1 * 64 + j * 16 + rl;
        ushort4 o = { f2bf(acc[i][j][0] + bv.x), f2bf(acc[i][j][1] + bv.y),
                      f2bf(acc[i][j][2] + bv.z), f2bf(acc[i][j][3] + bv.w) };
        *(ushort4*)(qk + (size_t)r * 256 + n0 + np) = o;
      }
    }
  } else {
    #pragma unroll
    for (int i = 0; i < 4; ++i) {
      const int np = w0 * 64 + i * 16 + 4 * g;
      const int h = np >> 4, db = np & 15;
      const float4 bv = *(const float4*)(bias + 256 + np);
      const float ba[4] = {bv.x, bv.y, bv.z, bv.w};
      #pragma unroll
      for (int j = 0; j < 4; ++j) {
        const int r = row0 + w1 * 64 + j * 16 + rl;
        const int wn = r >> 6, m = r & 63;
        unsigned short* dst = vt + (((size_t)wn * 8 + h) << 10) + m;
        #pragma unroll
        for (int e = 0; e < 4; ++e)
          dst[(db + e) * 64] = f2bf(acc[i][j][e] + ba[e]);
      }
    }
  }
}

// ---------------- K3: MFMA window attention (16x16x32 only), one wave per (window, head) ----------------
__global__ __launch_bounds__(256, 2) void k3_attn(
    const unsigned short* __restrict__ qk,
    const unsigned short* __restrict__ vt,
    const float* __restrict__ table,
    unsigned short* __restrict__ attn)
{
  __shared__ float Tb[1800];
  __shared__ __align__(16) unsigned short Pl[4][4096];   // per-wave P [r][m] bf16, XOR-swizzled
  const int t = threadIdx.x;
  for (int i = t; i < 1800; i += 256) Tb[i] = table[i];
  __syncthreads();
  const int l = t & 63, w = t >> 6;
  const int id = blockIdx.x * 4 + w;
  const int win = id >> 3, h = id & 7;
  const int g = l >> 4, rl = l & 15;
  // ---- QK^T via 16x16x32, K zero-padded (head_dim = 16 -> lanes g>=2 hold zeros) ----
  const unsigned short* qbase = qk + (size_t)win * 64 * 256 + h * 16;
  const short8v zz = {0,0,0,0,0,0,0,0};
  short8v qf[4], kf[4];
  if (g < 2) {
    #pragma unroll
    for (int rf = 0; rf < 4; ++rf)
      qf[rf] = *(const short8v*)(qbase + (size_t)(rf * 16 + rl) * 256 + g * 8);
    #pragma unroll
    for (int mf = 0; mf < 4; ++mf)
      kf[mf] = *(const short8v*)(qbase + 128 + (size_t)(mf * 16 + rl) * 256 + g * 8);
  } else {
    #pragma unroll
    for (int i = 0; i < 4; ++i) { qf[i] = zz; kf[i] = zz; }
  }
  const f32x4 z = {0.f, 0.f, 0.f, 0.f};
  f32x4 s[4][4];
  #pragma unroll
  for (int mf = 0; mf < 4; ++mf)
    #pragma unroll
    for (int rf = 0; rf < 4; ++rf)
      s[mf][rf] = mfma32(kf[mf], qf[rf], z);   // S^T: m = mf*16+4g+e, r = rf*16+rl
  // ---- bias + softmax (m runs over lanes sharing rl: xor 16/32) ----
  float sum[4];
  #pragma unroll
  for (int rf = 0; rf < 4; ++rf) {
    const int r = rf * 16 + rl, i1 = r >> 3, j1 = r & 7;
    float mx = -1e30f;
    #pragma unroll
    for (int mf = 0; mf < 4; ++mf)
      #pragma unroll
      for (int e = 0; e < 4; ++e) {
        const int m = mf * 16 + g * 4 + e;
        const int i2 = m >> 3, j2 = m & 7;
        const float v = s[mf][rf][e] * 0.25f + Tb[((i1 - i2 + 7) * 15 + (j1 - j2 + 7)) * 8 + h];
        s[mf][rf][e] = v;
        mx = fmaxf(mx, v);
      }
    mx = fmaxf(mx, __shfl_xor(mx, 16));
    mx = fmaxf(mx, __shfl_xor(mx, 32));
    float sm = 0.f;
    #pragma unroll
    for (int mf = 0; mf < 4; ++mf)
      #pragma unroll
      for (int e = 0; e < 4; ++e) {
        const float ev = __expf(s[mf][rf][e] - mx);
        s[mf][rf][e] = ev;
        sm += ev;
      }
    sm += __shfl_xor(sm, 16);
    sm += __shfl_xor(sm, 32);
    sum[rf] = sm;
  }
  // ---- pack P to bf16 and round-trip through per-wave LDS (intra-wave, no barrier) ----
  char* Pw = (char*)&Pl[w][0];
  #pragma unroll
  for (int rf = 0; rf < 4; ++rf) {
    const int r = rf * 16 + rl;
    const int swz = (r & 7) << 4;
    #pragma unroll
    for (int mf = 0; mf < 4; ++mf) {
      uint2 u;
      u.x = (unsigned)f2bf(s[mf][rf][0]) | ((unsigned)f2bf(s[mf][rf][1]) << 16);
      u.y = (unsigned)f2bf(s[mf][rf][2]) | ((unsigned)f2bf(s[mf][rf][3]) << 16);
      *(uint2*)(Pw + ((r * 128 + mf * 32 + g * 8) ^ swz)) = u;
    }
  }
  // ---- PV: O^T = V^T (A) x P^T (B), K = 32, 2 K-blocks ----
  const unsigned short* vb = vt + (((size_t)win * 8 + h) << 10) + rl * 64 + g * 8;
  f32x4 o[4];
  #pragma unroll
  for (int rf = 0; rf < 4; ++rf) o[rf] = z;
  #pragma unroll
  for (int c = 0; c < 2; ++c) {
    const short8v va = *(const short8v*)(vb + c * 32);
    #pragma unroll
    for (int rf = 0; rf < 4; ++rf) {
      const int r = rf * 16 + rl;
      const short8v pb = *(const short8v*)(Pw + ((r * 128 + c * 64 + g * 16) ^ ((r & 7) << 4)));
      o[rf] = mfma32(va, pb, o[rf]);
    }
  }
  #pragma unroll
  for (int rf = 0; rf < 4; ++rf) {
    const float inv = 1.f / sum[rf];
    const int r = rf * 16 + rl;
    ushort4 ov = { f2bf(o[rf][0] * inv), f2bf(o[rf][1] * inv),
                   f2bf(o[rf][2] * inv), f2bf(o[rf][3] * inv) };
    *(ushort4*)(attn + ((size_t)win * 64 + r) * 128 + h * 16 + g * 4) = ov;
  }
}

// ---------------- K4: proj MFMA + window reverse + unshift + residual -> d_out (f32) ----------------
__global__ __launch_bounds__(256, 2) void k4_proj(
    const unsigned short* __restrict__ A,
    const unsigned short* __restrict__ Wb,
    const float* __restrict__ bias,
    const float* __restrict__ xin,
    float* __restrict__ out)
{
  __shared__ __align__(16) short At[128 * 128];
  __shared__ __align__(16) short Bt[128 * 128];
  const int t = threadIdx.x;
  const int row0 = blockIdx.x * 128;
  stage128(Wb, 128, At);
  stage128(A + (size_t)row0 * 128, 128, Bt);
  __syncthreads();
  const int l = t & 63, w = t >> 6, w0 = w & 1, w1 = w >> 1;
  const int g = l >> 4, rl = l & 15;
  const f32x4 z = {0.f, 0.f, 0.f, 0.f};
  f32x4 acc[4][4];
  #pragma unroll
  for (int i = 0; i < 4; ++i)
    #pragma unroll
    for (int j = 0; j < 4; ++j) acc[i][j] = z;
  #pragma unroll
  for (int kk = 0; kk < 4; ++kk) {
    short8v a[4], b[4];
    #pragma unroll
    for (int i = 0; i < 4; ++i) a[i] = frag_ld(At, w0 * 64 + i * 16 + rl, kk * 4 + g);
    #pragma unroll
    for (int j = 0; j < 4; ++j) b[j] = frag_ld(Bt, w1 * 64 + j * 16 + rl, kk * 4 + g);
    #pragma unroll
    for (int i = 0; i < 4; ++i)
      #pragma unroll
      for (int j = 0; j < 4; ++j)
        acc[i][j] = mfma32(a[i], b[j], acc[i][j]);
  }
  #pragma unroll
  for (int i = 0; i < 4; ++i) {
    const int c = w0 * 64 + i * 16 + 4 * g;
    const float4 bv = *(const float4*)(bias + c);
    #pragma unroll
    for (int j = 0; j < 4; ++j) {
      const int r = row0 + w1 * 64 + j * 16 + rl;
      const int wn = r >> 6, n = r & 63;
      const int b_ = wn >> 10, rem = wn & 1023;
      const int wh = rem >> 5, ww = rem & 31;
      const int si = n >> 3, sj = n & 7;
      const int hd = (wh * 8 + si + 4) & 255;
      const int wd = (ww * 8 + sj + 4) & 255;
      const size_t off = (((size_t)b_ << 16) + hd * 256 + wd) * 128 + c;
      const float4 xv = *(const float4*)(xin + off);
      float4 o = { xv.x + acc[i][j][0] + bv.x, xv.y + acc[i][j][1] + bv.y,
                   xv.z + acc[i][j][2] + bv.z, xv.w + acc[i][j][3] + bv.w };
      *(float4*)(out + off) = o;
    }
  }
}

// ---------------- K5: fused LN2 + fc1 + GELU + fc2 + residual (MFMA) ----------------
__global__ __launch_bounds__(256, 2) void k5_mlp(
    const float* x2,
    const float* __restrict__ gw, const float* __restrict__ gb,
    const unsigned short* __restrict__ w1b, const float* __restrict__ b1,
    const unsigned short* __restrict__ w2b, const float* __restrict__ b2,
    float* out)
{
  __shared__ __align__(16) short Xt[64 * 128];
  __shared__ __align__(16) short Ht[64 * 128];
  __shared__ __align__(16) short Wt[128 * 128];
  const int t = threadIdx.x;
  const size_t row0 = (size_t)blockIdx.x * 64;
  {
    // FIXED: 4 threads per row over 64 rows (was 2 threads/row over 128 rows -> OOB
    // global read on the last block + Xt overflow).
    const int rr = t >> 2, qq = t & 3;
    const float* src = x2 + (row0 + rr) * 128 + qq * 32;
    float v[32]; float s = 0.f, ss = 0.f;
    #pragma unroll
    for (int q = 0; q < 8; ++q) {
      const float4 a4 = *(const float4*)(src + q * 4);
      v[q*4+0] = a4.x; v[q*4+1] = a4.y; v[q*4+2] = a4.z; v[q*4+3] = a4.w;
      s  += a4.x + a4.y + a4.z + a4.w;
      ss += a4.x*a4.x + a4.y*a4.y + a4.z*a4.z + a4.w*a4.w;
    }
    s += __shfl_xor(s, 1); ss += __shfl_xor(ss, 1);
    s += __shfl_xor(s, 2); ss += __shfl_xor(ss, 2);
    const float mean = s * 0.0078125f;
    const float rstd = rsqrtf(ss * 0.0078125f - mean * mean + LNEPS);
    #pragma unroll
    for (int cc = 0; cc < 4; ++cc) {
      const int col = qq * 32 + cc * 8;
      const float4 g0 = *(const float4*)(gw + col), g1 = *(const float4*)(gw + col + 4);
      const float4 c0 = *(const float4*)(gb + col), c1 = *(const float4*)(gb + col + 4);
      uint4 pk;
      pk.x = (unsigned)f2bf((v[cc*8+0]-mean)*rstd*g0.x + c0.x)
           | ((unsigned)f2bf((v[cc*8+1]-mean)*rstd*g0.y + c0.y) << 16);
      pk.y = (unsigned)f2bf((v[cc*8+2]-mean)*rstd*g0.z + c0.z)
           | ((unsigned)f2bf((v[cc*8+3]-mean)*rstd*g0.w + c0.w) << 16);
      pk.z = (unsigned)f2bf((v[cc*8+4]-mean)*rstd*g1.x + c1.x)
           | ((unsigned)f2bf((v[cc*8+5]-mean)*rstd*g1.y + c1.y) << 16);
      pk.w = (unsigned)f2bf((v[cc*8+6]-mean)*rstd*g1.z + c1.z)
           | ((unsigned)f2bf((v[cc*8+7]-mean)*rstd*g1.w + c1.w) << 16);
      const int chunk = qq * 4 + cc;
      *(uint4*)((char*)Xt + rr * 256 + ((chunk ^ (rr & 7)) << 4)) = pk;
    }
  }
  const int l = t & 63, w = t >> 6, w0 = w & 1, w1 = w >> 1;
  const int g = l >> 4, rl = l & 15;
  const f32x4 z = {0.f, 0.f, 0.f, 0.f};
  f32x4 oacc[4][2];
  #pragma unroll
  for (int i = 0; i < 4; ++i) { oacc[i][0] = z; oacc[i][1] = z; }
  for (int sb = 0; sb < 4; ++sb) {
    __syncthreads();
    stage128(w1b + (size_t)sb * 128 * 128, 128, Wt);
    __syncthreads();
    f32x4 hacc[4][2];
    #pragma unroll
    for (int i = 0; i < 4; ++i) { hacc[i][0] = z; hacc[i][1] = z; }
    #pragma unroll
    for (int kk = 0; kk < 4; ++kk) {
      short8v a[4], b[2];
      #pragma unroll
      for (int i = 0; i < 4; ++i) a[i] = frag_ld(Wt, w0 * 64 + i * 16 + rl, kk * 4 + g);
      #pragma unroll
      for (int j = 0; j < 2; ++j) b[j] = frag_ld(Xt, w1 * 32 + j * 16 + rl, kk * 4 + g);
      #pragma unroll
      for (int i = 0; i < 4; ++i)
        #pragma unroll
        for (int j = 0; j < 2; ++j)
          hacc[i][j] = mfma32(a[i], b[j], hacc[i][j]);
    }
    __syncthreads();
    #pragma unroll
    for (int i = 0; i < 4; ++i) {
      const int cl = w0 * 64 + i * 16 + 4 * g;
      const float4 b1v = *(const float4*)(b1 + sb * 128 + cl);
      const float ba[4] = {b1v.x, b1v.y, b1v.z, b1v.w};
      #pragma unroll
      for (int j = 0; j < 2; ++j) {
        const int r = w1 * 32 + j * 16 + rl;
        ushort4 p;
        p.x = f2bf(gelu_f(hacc[i][j][0] + ba[0]));
        p.y = f2bf(gelu_f(hacc[i][j][1] + ba[1]));
        p.z = f2bf(gelu_f(hacc[i][j][2] + ba[2]));
        p.w = f2bf(gelu_f(hacc[i][j][3] + ba[3]));
        const int chunk = cl >> 3, inner = (cl & 7) * 2;
        *(ushort4*)((char*)Ht + r * 256 + ((chunk ^ (r & 7)) << 4) + inner) = p;
      }
    }
    stage128(w2b + (size_t)sb * 128, 512, Wt);
    __syncthreads();
    #pragma unroll
    for (int kk = 0; kk < 4; ++kk) {
      short8v a[4], b[2];
      #pragma unroll
      for (int i = 0; i < 4; ++i) a[i] = frag_ld(Wt, w0 * 64 + i * 16 + rl, kk * 4 + g);
      #pragma unroll
      for (int j = 0; j < 2; ++j) b[j] = frag_ld(Ht, w1 * 32 + j * 16 + rl, kk * 4 + g);
      #pragma unroll
      for (int i = 0; i < 4; ++i)
        #pragma unroll
        for (int j = 0; j < 2; ++j)
          oacc[i][j] = mfma32(a[i], b[j], oacc[i][j]);
    }
  }
  #pragma unroll
  for (int i = 0; i < 4; ++i) {
    const int c = w0 * 64 + i * 16 + 4 * g;
    const float4 bv = *(const float4*)(b2 + c);
    #pragma unroll
    for (int j = 0; j < 2; ++j) {
      const size_t r = row0 + w1 * 32 + j * 16 + rl;
      const float4 xv = *(const float4*)(x2 + r * 128 + c);
      float4 o = { xv.x + oacc[i][j][0] + bv.x, xv.y + oacc[i][j][1] + bv.y,
                   xv.z + oacc[i][j][2] + bv.z, xv.w + oacc[i][j][3] + bv.w };
      *(float4*)(out + r * 128 + c) = o;
    }
  }
}

extern "C" void kernel_launch(void* const* d_in, const int* in_sizes, int n_in,
                              void* d_out, int out_size, void* d_ws, size_t ws_size,
                              hipStream_t stream)
{
  const float* x    = (const float*)d_in[0];
  const float* n1w  = (const float*)d_in[1];
  const float* n1b  = (const float*)d_in[2];
  const float* qkvw = (const float*)d_in[3];
  const float* qkvB = (const float*)d_in[4];
  const float* relb = (const float*)d_in[5];
  const float* pw   = (const float*)d_in[6];
  const float* pb   = (const float*)d_in[7];
  const float* n2w  = (const float*)d_in[8];
  const float* n2b  = (const float*)d_in[9];
  const float* w1   = (const float*)d_in[10];
  const float* b1   = (const float*)d_in[11];
  const float* w2   = (const float*)d_in[12];
  const float* b2   = (const float*)d_in[13];
  float* out = (float*)d_out;

  unsigned short* winb = (unsigned short*)d_ws;        // 16,777,216 el (LN1 out; reused as attn out)
  unsigned short* qkb  = winb + 16777216;              // 33,554,432 el  Q|K interleaved [row][256]
  unsigned short* vtb  = qkb + 33554432;               // 16,777,216 el  V^T per (win,head): [16][64]
  unsigned short* wb   = vtb + 16777216;               // 196,608 el  bf16 weights
  unsigned short* qkvw_b = wb;
  unsigned short* pw_b   = wb + 49152;
  unsigned short* w1_b   = wb + 65536;
  unsigned short* w2_b   = wb + 131072;

  k0_cvt<<<192, 256, 0, stream>>>(qkvw, pw, w1, w2, wb);
  k1_ln1_window<<<32768, 256, 0, stream>>>(x, n1w, n1b, winb);
  k2_qkv<<<dim3(1024, 3), 256, 0, stream>>>(winb, qkvw_b, qkvB, qkb, vtb);
  k3_attn<<<4096, 256, 0, stream>>>(qkb, vtb, relb, winb);
  k4_proj<<<1024, 256, 0, stream>>>(winb, pw_b, pb, x, out);
  k5_mlp<<<2048, 256, 0, stream>>>(out, n2w, n2b, w1_b, b1, w2_b, b2, out);
}